// Round 9
// baseline (344.505 us; speedup 1.0000x reference)
//
#include <hip/hip_runtime.h>

#define B_ 4
#define S_ 2048
#define D_ 512
#define H_ 8

typedef __attribute__((ext_vector_type(8))) __bf16 bf16x8;
typedef __attribute__((ext_vector_type(4))) float f32x4;

#define NEGBIG  -1.442695040e9f          // -1e9 * log2(e): masks live in exp2 domain
#define QSCALE  0.18033688011112042f     // 0.125 * log2(e) folded into Q

// pack two floats -> two bf16 (RNE-ish, ties-up): 2 adds + 1 v_perm
__device__ __forceinline__ unsigned pack_rn(float a, float b) {
    union { float f; unsigned u; } ua, ub; ua.f = a; ub.f = b;
    return __builtin_amdgcn_perm(ub.u + 0x8000u, ua.u + 0x8000u, 0x07060302u);
}
__device__ __forceinline__ float b2f_lo(unsigned u) {
    union { unsigned u; float f; } v; v.u = u << 16; return v.f;
}
__device__ __forceinline__ float b2f_hi(unsigned u) {
    union { unsigned u; float f; } v; v.u = u & 0xFFFF0000u; return v.f;
}

// ---------------------------------------------------------------------------
// Coalesced weight cast+transpose: Wt[n][k] = bf16(W[k][n]), via LDS tile.
// z==4: convert attention mask ints to floats in the exp2 domain.
// ---------------------------------------------------------------------------
__global__ __launch_bounds__(256) void cast_wt(
    const float* __restrict__ Wq, const float* __restrict__ Wk,
    const float* __restrict__ Wv, const float* __restrict__ Wo,
    const int* __restrict__ amask,
    unsigned short* __restrict__ Tq, unsigned short* __restrict__ Tk,
    unsigned short* __restrict__ Tv, unsigned short* __restrict__ To,
    float* __restrict__ maskF)
{
    int z = blockIdx.z;
    int tid = threadIdx.x;
    if (z == 4) {                 // mask -> float, 64 blocks x 128 elements
        int lin = (blockIdx.y * 8 + blockIdx.x) * 128 + tid;
        if (tid < 128) maskF[lin] = amask[lin] ? 0.f : NEGBIG;
        return;
    }
    const float* W = (z == 0) ? Wq : (z == 1) ? Wk : (z == 2) ? Wv : Wo;
    unsigned short* T = (z == 0) ? Tq : (z == 1) ? Tk : (z == 2) ? Tv : To;
    int n0 = blockIdx.x * 64, k0 = blockIdx.y * 64;

    __shared__ float Ts[64][69];
    #pragma unroll
    for (int it = 0; it < 4; it++) {
        int lin = tid + it * 256;
        int kr = lin >> 4, c4 = (lin & 15) * 4;
        float4 v = *(const float4*)&W[(k0 + kr) * 512 + n0 + c4];
        Ts[kr][c4 + 0] = v.x; Ts[kr][c4 + 1] = v.y;
        Ts[kr][c4 + 2] = v.z; Ts[kr][c4 + 3] = v.w;
    }
    __syncthreads();
    int n = tid >> 2, kc = tid & 3;
    unsigned p[8];
    #pragma unroll
    for (int j = 0; j < 8; j++)
        p[j] = pack_rn(Ts[kc * 16 + 2 * j][n], Ts[kc * 16 + 2 * j + 1][n]);
    unsigned short* dst = &T[(n0 + n) * 512 + k0 + kc * 16];
    *(uint4*)dst       = *(uint4*)&p[0];
    *(uint4*)(dst + 8) = *(uint4*)&p[4];
}

// ---------------------------------------------------------------------------
// QKV projection GEMM with FUSED fp32->bf16 activation cast in the staging
// path (no separate cast_x kernel). 128x128 tile, 4 waves (2x2 of 64).
// z=0 (Q): A=Wtq (bf16, m=feature), B=query (fp32->bf16, n=s) -> (bh,s,d),
//          scaled by 0.125*log2e.
// z=1 (K): A=Wtk, B=value -> (bh,s,d).
// z=2 (V): A=value (fp32->bf16, m=s), B=Wtv (bf16) -> transposed (bh,d,s).
// ---------------------------------------------------------------------------
__global__ __launch_bounds__(256) void proj_qkv_mfma(
    const float* __restrict__ Xq, const float* __restrict__ Xv,
    const unsigned short* __restrict__ Wtq, const unsigned short* __restrict__ Wtk,
    const unsigned short* __restrict__ Wtv,
    const float* __restrict__ bq, const float* __restrict__ bk,
    const float* __restrict__ bv,
    unsigned short* __restrict__ Qb, unsigned short* __restrict__ Kb,
    unsigned short* __restrict__ VtG)
{
    const int z = blockIdx.z;
    const float* Xf          = (z == 0) ? Xq : Xv;        // fp32 activation
    const unsigned short* Wt = (z == 0) ? Wtq : (z == 1) ? Wtk : Wtv;
    const float* bias        = (z == 0) ? bq  : (z == 1) ? bk  : bv;
    const int m0 = (z < 2) ? blockIdx.y * 128 : blockIdx.x * 128;
    const int n0 = (z < 2) ? blockIdx.x * 128 : blockIdx.y * 128;

    const int tid = threadIdx.x;
    const int w = tid >> 6, lane = tid & 63;
    const int l15 = lane & 15, quad = lane >> 4;
    const int wm = (w >> 1) * 64, wn = (w & 1) * 64;

    __shared__ unsigned short As[128 * 72];
    __shared__ unsigned short Bs[128 * 72];

    f32x4 acc[4][4];
    #pragma unroll
    for (int i = 0; i < 4; i++)
        #pragma unroll
        for (int j = 0; j < 4; j++) acc[i][j] = (f32x4){0.f, 0.f, 0.f, 0.f};

    for (int k0 = 0; k0 < 512; k0 += 64) {
        __syncthreads();
        // weight tile (bf16 copy): As for z<2, Bs for z==2
        {
            unsigned short* Wdst = (z < 2) ? As : Bs;
            const int wrow0 = (z < 2) ? m0 : n0;
            #pragma unroll
            for (int it = 0; it < 2; it++) {
                int lin = tid + it * 256;
                int row = lin >> 2, c2 = (lin & 3) * 2;
                *(uint4*)&Wdst[row * 72 + c2 * 8]     = *(const uint4*)&Wt[(wrow0 + row) * 512 + k0 + c2 * 8];
                *(uint4*)&Wdst[row * 72 + c2 * 8 + 8] = *(const uint4*)&Wt[(wrow0 + row) * 512 + k0 + c2 * 8 + 8];
            }
        }
        // activation tile (fp32 -> bf16 in flight): Bs for z<2, As for z==2
        {
            unsigned short* Xdst = (z < 2) ? Bs : As;
            const int xrow0 = (z < 2) ? n0 : m0;
            #pragma unroll
            for (int it = 0; it < 8; it++) {
                int lin = tid + it * 256;
                int row = lin >> 4, c4 = (lin & 15) * 4;
                float4 v = *(const float4*)&Xf[(xrow0 + row) * 512 + k0 + c4];
                uint2 pp; pp.x = pack_rn(v.x, v.y); pp.y = pack_rn(v.z, v.w);
                *(uint2*)&Xdst[row * 72 + c4] = pp;
            }
        }
        __syncthreads();
        #pragma unroll
        for (int kc = 0; kc < 2; kc++) {
            bf16x8 a[4], bb[4];
            #pragma unroll
            for (int i = 0; i < 4; i++)
                a[i] = *(const bf16x8*)&As[(wm + 16 * i + l15) * 72 + kc * 32 + quad * 8];
            #pragma unroll
            for (int j = 0; j < 4; j++)
                bb[j] = *(const bf16x8*)&Bs[(wn + 16 * j + l15) * 72 + kc * 32 + quad * 8];
            #pragma unroll
            for (int i = 0; i < 4; i++)
                #pragma unroll
                for (int j = 0; j < 4; j++)
                    acc[i][j] = __builtin_amdgcn_mfma_f32_16x16x32_bf16(a[i], bb[j], acc[i][j], 0, 0, 0);
        }
    }

    if (z == 2) {
        #pragma unroll
        for (int j = 0; j < 4; j++) {
            int N = n0 + wn + 16 * j + l15;
            float bv_ = bias[N];
            int h = N >> 6, d = N & 63;
            #pragma unroll
            for (int i = 0; i < 4; i++) {
                int Mb = m0 + wm + 16 * i + quad * 4;
                int b = Mb >> 11, s = Mb & 2047;
                uint2 o;
                o.x = pack_rn(acc[i][j][0] + bv_, acc[i][j][1] + bv_);
                o.y = pack_rn(acc[i][j][2] + bv_, acc[i][j][3] + bv_);
                *(uint2*)&VtG[((b * H_ + h) * 64 + d) * 2048 + s] = o;
            }
        }
    } else {
        unsigned short* dst = (z == 0) ? Qb : Kb;
        const float scale = (z == 0) ? QSCALE : 1.0f;
        #pragma unroll
        for (int j = 0; j < 4; j++) {
            int sg = n0 + wn + 16 * j + l15;
            int b = sg >> 11, s = sg & 2047;
            #pragma unroll
            for (int i = 0; i < 4; i++) {
                int F = m0 + wm + 16 * i + quad * 4;
                int h = F >> 6, d = F & 63;
                float4 b4 = *(const float4*)&bias[F];
                uint2 o;
                o.x = pack_rn((acc[i][j][0] + b4.x) * scale, (acc[i][j][1] + b4.y) * scale);
                o.y = pack_rn((acc[i][j][2] + b4.z) * scale, (acc[i][j][3] + b4.w) * scale);
                *(uint2*)&dst[((b * H_ + h) * 2048 + s) * 64 + d] = o;
            }
        }
    }
}

// ---------------------------------------------------------------------------
// Split-K MFMA flash attention, fixed-shift softmax, XCD-clustered swizzle.
// 1-D grid of 1024; decode so all 16 q-blocks of one (bh, key-chunk) pair
// share lin&7 (same XCD under round-robin dispatch) -> K/V L2-resident.
// K via double-buffered LDS (1 barrier/tile); V frags REGISTER double-
// buffered (prefetched one tile ahead -> HBM latency covered by full tile).
// Fixed shift (mq) makes chunk partials additive; li via ones-MFMA.
// ---------------------------------------------------------------------------
__global__ __launch_bounds__(256, 4) void flash_mfma(
    const unsigned short* __restrict__ Qg, const unsigned short* __restrict__ Kg,
    const unsigned short* __restrict__ VtG, const float* __restrict__ maskF,
    unsigned short* __restrict__ O0, unsigned short* __restrict__ O1,
    float* __restrict__ Lpart)
{
    const int lin = blockIdx.x;
    const int xcd = lin & 7, slot = lin >> 3;
    const int qi = slot & 15, pp = slot >> 4;
    const int pair = xcd * 8 + pp;           // 0..63 = (bh, z)
    const int bh = pair >> 1, z = pair & 1;
    const int b = bh >> 3, h = bh & 7;
    const int q0 = qi * 128;
    const int kbeg = z * 1024;
    const int tid = threadIdx.x;
    const int w = tid >> 6, lane = tid & 63;
    const int l15 = lane & 15, quad = lane >> 4;

    __shared__ unsigned short Ks[2][64 * 72];    // double-buffered K tile [key][d]
    __shared__ unsigned short Ps[4][32 * 72];    // per-wave P region [q][key]
    __shared__ float Km[4][64];                  // per-wave key-mask broadcast

    const float* mfb = maskF + b * 2048;
    unsigned short* pw = &Ps[w][0];

    // Q fragments (B-operand) + query mask, resident
    bf16x8 qf[2][2];
    float mq[2];
    #pragma unroll
    for (int qb = 0; qb < 2; qb++) {
        int qrow = q0 + w * 32 + qb * 16 + l15;
        const unsigned short* p = &Qg[(bh * 2048 + qrow) * 64 + quad * 8];
        qf[qb][0] = *(const bf16x8*)p;
        qf[qb][1] = *(const bf16x8*)(p + 32);
        mq[qb] = mfb[qrow];
    }

    // ones fragment for the li-MFMA
    bf16x8 ones;
    #pragma unroll
    for (int i = 0; i < 8; i++) ones[i] = (__bf16)1.0f;

    // K staging: thread -> (row = tid>>2, 2 chunks at (tid&3)*2) of 64x64 tile
    const int srow = tid >> 2;
    const int sch  = (tid & 3) * 2;
    const unsigned short* kgb = Kg + (long)bh * 2048 * 64;
    const unsigned short* vgb = VtG + (long)bh * 64 * 2048;

    *(uint4*)&Ks[0][srow * 72 + sch * 8]     = *(const uint4*)&kgb[(kbeg + srow) * 64 + sch * 8];
    *(uint4*)&Ks[0][srow * 72 + sch * 8 + 8] = *(const uint4*)&kgb[(kbeg + srow) * 64 + sch * 8 + 8];
    float mfreg = mfb[kbeg + lane];              // mask prefetch for tile 0

    // V fragments for tile 0 (register prefetch buffer)
    bf16x8 vf[2][4][2];
    #pragma unroll
    for (int dt = 0; dt < 4; dt++)
        #pragma unroll
        for (int kc = 0; kc < 2; kc++)
            vf[0][dt][kc] = *(const bf16x8*)&vgb[(dt * 16 + l15) * 2048 + kbeg + kc * 32 + quad * 8];

    f32x4 accO[2][4];
    f32x4 accL[2];
    #pragma unroll
    for (int qb = 0; qb < 2; qb++) {
        accL[qb] = (f32x4){0.f, 0.f, 0.f, 0.f};
        #pragma unroll
        for (int dt = 0; dt < 4; dt++) accO[qb][dt] = (f32x4){0.f, 0.f, 0.f, 0.f};
    }

    __syncthreads();

    for (int tl = 0; tl < 16; tl++) {
        const int kt = kbeg + tl * 64;
        const int ktn = (tl < 15) ? kt + 64 : kt;
        const int cur = tl & 1, nxt = cur ^ 1;

        // [A] global loads for NEXT tile: V frags (reg dbuf), K staging, mask
        #pragma unroll
        for (int dt = 0; dt < 4; dt++)
            #pragma unroll
            for (int kc = 0; kc < 2; kc++)
                vf[nxt][dt][kc] = *(const bf16x8*)&vgb[(dt * 16 + l15) * 2048 + ktn + kc * 32 + quad * 8];
        uint4 kst0 = *(const uint4*)&kgb[(ktn + srow) * 64 + sch * 8];
        uint4 kst1 = *(const uint4*)&kgb[(ktn + srow) * 64 + sch * 8 + 8];
        Km[w][lane] = mfreg;                 // this tile's mask -> per-wave LDS
        mfreg = mfb[ktn + lane];             // prefetch next tile's mask

        f32x4 kmf[4];
        #pragma unroll
        for (int nt = 0; nt < 4; nt++)
            kmf[nt] = *(const f32x4*)&Km[w][nt * 16 + quad * 4];

        // [B] QK from LDS buf[cur]: S^T (rows=key, cols=q)
        bf16x8 kf[4][2];
        #pragma unroll
        for (int nt = 0; nt < 4; nt++)
            #pragma unroll
            for (int kc = 0; kc < 2; kc++)
                kf[nt][kc] = *(const bf16x8*)&Ks[cur][(nt * 16 + l15) * 72 + kc * 32 + quad * 8];
        f32x4 sc[2][4];
        #pragma unroll
        for (int qb = 0; qb < 2; qb++)
            #pragma unroll
            for (int nt = 0; nt < 4; nt++) {
                sc[qb][nt] = kmf[nt] + mq[qb];   // masks as C-init: exact quantization
                #pragma unroll
                for (int kc = 0; kc < 2; kc++)
                    sc[qb][nt] = __builtin_amdgcn_mfma_f32_16x16x32_bf16(
                        kf[nt][kc], qf[qb][kc], sc[qb][nt], 0, 0, 0);
            }

        // [C] fixed-shift softmax: p = exp2(sc - mq). No max, no alpha.
        #pragma unroll
        for (int qb = 0; qb < 2; qb++) {
            #pragma unroll
            for (int nt = 0; nt < 4; nt++) {
                float p0 = __builtin_amdgcn_exp2f(sc[qb][nt][0] - mq[qb]);
                float p1 = __builtin_amdgcn_exp2f(sc[qb][nt][1] - mq[qb]);
                float p2 = __builtin_amdgcn_exp2f(sc[qb][nt][2] - mq[qb]);
                float p3 = __builtin_amdgcn_exp2f(sc[qb][nt][3] - mq[qb]);
                uint2 pp2;
                pp2.x = pack_rn(p0, p1);
                pp2.y = pack_rn(p2, p3);
                *(uint2*)&pw[(qb * 16 + l15) * 72 + nt * 16 + quad * 4] = pp2;
            }
        }

        // [D] PV + li: O^T += Vt x P^T ; li += ones x P^T  (uses vf[cur])
        #pragma unroll
        for (int qb = 0; qb < 2; qb++) {
            bf16x8 pf0 = *(const bf16x8*)&pw[(qb * 16 + l15) * 72 + quad * 8];
            bf16x8 pf1 = *(const bf16x8*)&pw[(qb * 16 + l15) * 72 + 32 + quad * 8];
            accL[qb] = __builtin_amdgcn_mfma_f32_16x16x32_bf16(ones, pf0, accL[qb], 0, 0, 0);
            accL[qb] = __builtin_amdgcn_mfma_f32_16x16x32_bf16(ones, pf1, accL[qb], 0, 0, 0);
            #pragma unroll
            for (int dt = 0; dt < 4; dt++) {
                accO[qb][dt] = __builtin_amdgcn_mfma_f32_16x16x32_bf16(
                    vf[cur][dt][0], pf0, accO[qb][dt], 0, 0, 0);
                accO[qb][dt] = __builtin_amdgcn_mfma_f32_16x16x32_bf16(
                    vf[cur][dt][1], pf1, accO[qb][dt], 0, 0, 0);
            }
        }

        // [E] commit next K tile to LDS, [F] barrier
        *(uint4*)&Ks[nxt][srow * 72 + sch * 8]     = kst0;
        *(uint4*)&Ks[nxt][srow * 72 + sch * 8 + 8] = kst1;
        __syncthreads();
    }

    // epilogue: UNNORMALIZED partial O (bf16) + partial li per q row
    unsigned short* Opz = z ? O1 : O0;
    float* Lz = Lpart + z * (32 * 2048);
    #pragma unroll
    for (int qb = 0; qb < 2; qb++) {
        int q = q0 + w * 32 + qb * 16 + l15;
        int obase = (b * 2048 + q) * 512 + h * 64 + quad * 4;
        #pragma unroll
        for (int dt = 0; dt < 4; dt++) {
            uint2 o;
            o.x = pack_rn(accO[qb][dt][0], accO[qb][dt][1]);
            o.y = pack_rn(accO[qb][dt][2], accO[qb][dt][3]);
            *(uint2*)&Opz[obase + dt * 16] = o;
        }
        if (quad == 0) Lz[bh * 2048 + q] = accL[qb][0];
    }
}

// ---------------------------------------------------------------------------
// Output projection with FUSED split-K combine: during B staging,
// B[s][k] = bf16((O0+O1) / (li0+li1)). h = k0>>6 is constant per k-iter so
// one inv per thread per iteration. A=Wto -> epilogue is float4 stores.
// ---------------------------------------------------------------------------
__global__ __launch_bounds__(256) void proj_out_mfma(
    const unsigned short* __restrict__ O0, const unsigned short* __restrict__ O1,
    const float* __restrict__ Lpart, const unsigned short* __restrict__ Wto,
    const float* __restrict__ bo, float* __restrict__ out)
{
    const int m0 = blockIdx.y * 128, n0 = blockIdx.x * 128;
    const int tid = threadIdx.x;
    const int w = tid >> 6, lane = tid & 63;
    const int l15 = lane & 15, quad = lane >> 4;
    const int wm = (w >> 1) * 64, wn = (w & 1) * 64;

    __shared__ unsigned short As[128 * 72];
    __shared__ unsigned short Bs[128 * 72];

    f32x4 acc[4][4];
    #pragma unroll
    for (int i = 0; i < 4; i++)
        #pragma unroll
        for (int j = 0; j < 4; j++) acc[i][j] = (f32x4){0.f, 0.f, 0.f, 0.f};

    for (int k0 = 0; k0 < 512; k0 += 64) {
        const int h = k0 >> 6;
        __syncthreads();
        #pragma unroll
        for (int it = 0; it < 2; it++) {
            int lin = tid + it * 256;
            int row = lin >> 2, c2 = (lin & 3) * 2;
            // A: Wto bf16 copy
            *(uint4*)&As[row * 72 + c2 * 8]     = *(const uint4*)&Wto[(m0 + row) * 512 + k0 + c2 * 8];
            *(uint4*)&As[row * 72 + c2 * 8 + 8] = *(const uint4*)&Wto[(m0 + row) * 512 + k0 + c2 * 8 + 8];
            // B: fused combine of split-K partials
            int srow = n0 + row;
            int b = srow >> 11, s = srow & 2047;
            int li_idx = ((b * 8 + h) << 11) + s;
            float inv = 1.f / (Lpart[li_idx] + Lpart[32 * 2048 + li_idx]);
            long gofs = (long)srow * 512 + k0 + c2 * 8;
            #pragma unroll
            for (int half = 0; half < 2; half++) {
                uint4 a4 = *(const uint4*)&O0[gofs + half * 8];
                uint4 c4 = *(const uint4*)&O1[gofs + half * 8];
                uint4 o4;
                o4.x = pack_rn((b2f_lo(a4.x) + b2f_lo(c4.x)) * inv,
                               (b2f_hi(a4.x) + b2f_hi(c4.x)) * inv);
                o4.y = pack_rn((b2f_lo(a4.y) + b2f_lo(c4.y)) * inv,
                               (b2f_hi(a4.y) + b2f_hi(c4.y)) * inv);
                o4.z = pack_rn((b2f_lo(a4.z) + b2f_lo(c4.z)) * inv,
                               (b2f_hi(a4.z) + b2f_hi(c4.z)) * inv);
                o4.w = pack_rn((b2f_lo(a4.w) + b2f_lo(c4.w)) * inv,
                               (b2f_hi(a4.w) + b2f_hi(c4.w)) * inv);
                *(uint4*)&Bs[row * 72 + c2 * 8 + half * 8] = o4;
            }
        }
        __syncthreads();
        #pragma unroll
        for (int kc = 0; kc < 2; kc++) {
            bf16x8 a[4], bb[4];
            #pragma unroll
            for (int i = 0; i < 4; i++)
                a[i] = *(const bf16x8*)&As[(wm + 16 * i + l15) * 72 + kc * 32 + quad * 8];
            #pragma unroll
            for (int j = 0; j < 4; j++)
                bb[j] = *(const bf16x8*)&Bs[(wn + 16 * j + l15) * 72 + kc * 32 + quad * 8];
            #pragma unroll
            for (int i = 0; i < 4; i++)
                #pragma unroll
                for (int j = 0; j < 4; j++)
                    acc[i][j] = __builtin_amdgcn_mfma_f32_16x16x32_bf16(a[i], bb[j], acc[i][j], 0, 0, 0);
        }
    }

    #pragma unroll
    for (int j = 0; j < 4; j++) {
        int sg = n0 + wn + 16 * j + l15;
        #pragma unroll
        for (int i = 0; i < 4; i++) {
            int F = m0 + wm + 16 * i + quad * 4;
            float4 b4 = *(const float4*)&bo[F];
            float4 vv;
            vv.x = acc[i][j][0] + b4.x;
            vv.y = acc[i][j][1] + b4.y;
            vv.z = acc[i][j][2] + b4.z;
            vv.w = acc[i][j][3] + b4.w;
            *(float4*)&out[sg * 512 + F] = vv;
        }
    }
}

extern "C" void kernel_launch(void* const* d_in, const int* in_sizes, int n_in,
                              void* d_out, int out_size, void* d_ws, size_t ws_size,
                              hipStream_t stream)
{
    const float* query = (const float*)d_in[0];
    const float* value = (const float*)d_in[1];
    const int*   amask = (const int*)d_in[2];
    const float* Wq = (const float*)d_in[3];
    const float* bq = (const float*)d_in[4];
    const float* Wk = (const float*)d_in[5];
    const float* bk = (const float*)d_in[6];
    const float* Wv = (const float*)d_in[7];
    const float* bv = (const float*)d_in[8];
    const float* Wo = (const float*)d_in[9];
    const float* bo = (const float*)d_in[10];
    float* out = (float*)d_out;

    char* ws = (char*)d_ws;
    const size_t MB = 1 << 20;
    unsigned short* O0  = (unsigned short*)(ws);                  // 8 MB split-K partial O
    unsigned short* O1  = (unsigned short*)(ws + 8 * MB);         // 8 MB
    unsigned short* Wtq = (unsigned short*)(ws + 16 * MB);        // 0.5 MB each
    unsigned short* Wtk = (unsigned short*)(ws + 16 * MB + MB / 2);
    unsigned short* Wtv = (unsigned short*)(ws + 17 * MB);
    unsigned short* Wto = (unsigned short*)(ws + 17 * MB + MB / 2);
    unsigned short* Qb  = (unsigned short*)(ws + 18 * MB);        // 8 MB (bh,s,d)
    unsigned short* Kb  = (unsigned short*)(ws + 26 * MB);        // 8 MB (bh,s,d)
    unsigned short* VtG = (unsigned short*)(ws + 34 * MB);        // 8 MB (bh,d,s)
    float*          mF  = (float*)(ws + 50 * MB);                 // 32 KB float mask
    float*          Lp  = (float*)(ws + 51 * MB);                 // 512 KB li partials

    cast_wt<<<dim3(8, 8, 5), 256, 0, stream>>>(Wq, Wk, Wv, Wo, amask,
                                               Wtq, Wtk, Wtv, Wto, mF);
    proj_qkv_mfma<<<dim3(64, 4, 3), 256, 0, stream>>>(query, value, Wtq, Wtk, Wtv,
                                                      bq, bk, bv, Qb, Kb, VtG);
    flash_mfma<<<dim3(1024), 256, 0, stream>>>(Qb, Kb, VtG, mF, O0, O1, Lp);
    proj_out_mfma<<<dim3(64, 4), 256, 0, stream>>>(O0, O1, Lp, Wto, bo, out);
}

// Round 10
// 219.357 us; speedup vs baseline: 1.5705x; 1.5705x over previous
//
#include <hip/hip_runtime.h>

#define B_ 4
#define S_ 2048
#define D_ 512
#define H_ 8

typedef __attribute__((ext_vector_type(8))) __bf16 bf16x8;
typedef __attribute__((ext_vector_type(4))) float f32x4;

#define NEGBIG  -1.442695040e9f          // -1e9 * log2(e): masks live in exp2 domain
#define QSCALE  0.18033688011112042f     // 0.125 * log2(e) folded into Q

// pack two floats -> two bf16 (RNE-ish, ties-up): 2 adds + 1 v_perm
__device__ __forceinline__ unsigned pack_rn(float a, float b) {
    union { float f; unsigned u; } ua, ub; ua.f = a; ub.f = b;
    return __builtin_amdgcn_perm(ub.u + 0x8000u, ua.u + 0x8000u, 0x07060302u);
}
__device__ __forceinline__ float b2f_lo(unsigned u) {
    union { unsigned u; float f; } v; v.u = u << 16; return v.f;
}
__device__ __forceinline__ float b2f_hi(unsigned u) {
    union { unsigned u; float f; } v; v.u = u & 0xFFFF0000u; return v.f;
}

// ---------------------------------------------------------------------------
// Coalesced weight cast+transpose: Wt[n][k] = bf16(W[k][n]), via LDS tile.
// z==4: convert attention mask ints to floats in the exp2 domain.
// ---------------------------------------------------------------------------
__global__ __launch_bounds__(256) void cast_wt(
    const float* __restrict__ Wq, const float* __restrict__ Wk,
    const float* __restrict__ Wv, const float* __restrict__ Wo,
    const int* __restrict__ amask,
    unsigned short* __restrict__ Tq, unsigned short* __restrict__ Tk,
    unsigned short* __restrict__ Tv, unsigned short* __restrict__ To,
    float* __restrict__ maskF)
{
    int z = blockIdx.z;
    int tid = threadIdx.x;
    if (z == 4) {                 // mask -> float, 64 blocks x 128 elements
        int lin = (blockIdx.y * 8 + blockIdx.x) * 128 + tid;
        if (tid < 128) maskF[lin] = amask[lin] ? 0.f : NEGBIG;
        return;
    }
    const float* W = (z == 0) ? Wq : (z == 1) ? Wk : (z == 2) ? Wv : Wo;
    unsigned short* T = (z == 0) ? Tq : (z == 1) ? Tk : (z == 2) ? Tv : To;
    int n0 = blockIdx.x * 64, k0 = blockIdx.y * 64;

    __shared__ float Ts[64][69];
    #pragma unroll
    for (int it = 0; it < 4; it++) {
        int lin = tid + it * 256;
        int kr = lin >> 4, c4 = (lin & 15) * 4;
        float4 v = *(const float4*)&W[(k0 + kr) * 512 + n0 + c4];
        Ts[kr][c4 + 0] = v.x; Ts[kr][c4 + 1] = v.y;
        Ts[kr][c4 + 2] = v.z; Ts[kr][c4 + 3] = v.w;
    }
    __syncthreads();
    int n = tid >> 2, kc = tid & 3;
    unsigned p[8];
    #pragma unroll
    for (int j = 0; j < 8; j++)
        p[j] = pack_rn(Ts[kc * 16 + 2 * j][n], Ts[kc * 16 + 2 * j + 1][n]);
    unsigned short* dst = &T[(n0 + n) * 512 + k0 + kc * 16];
    *(uint4*)dst       = *(uint4*)&p[0];
    *(uint4*)(dst + 8) = *(uint4*)&p[4];
}

// ---------------------------------------------------------------------------
// QKV projection GEMM with FUSED fp32->bf16 activation cast in the staging
// path (no separate cast_x kernel). 128x128 tile, 4 waves (2x2 of 64).
// z=0 (Q): A=Wtq (bf16, m=feature), B=query (fp32->bf16, n=s) -> (bh,s,d),
//          scaled by 0.125*log2e.
// z=1 (K): A=Wtk, B=value -> (bh,s,d).
// z=2 (V): A=value (fp32->bf16, m=s), B=Wtv (bf16) -> transposed (bh,d,s).
// ---------------------------------------------------------------------------
__global__ __launch_bounds__(256) void proj_qkv_mfma(
    const float* __restrict__ Xq, const float* __restrict__ Xv,
    const unsigned short* __restrict__ Wtq, const unsigned short* __restrict__ Wtk,
    const unsigned short* __restrict__ Wtv,
    const float* __restrict__ bq, const float* __restrict__ bk,
    const float* __restrict__ bv,
    unsigned short* __restrict__ Qb, unsigned short* __restrict__ Kb,
    unsigned short* __restrict__ VtG)
{
    const int z = blockIdx.z;
    const float* Xf          = (z == 0) ? Xq : Xv;        // fp32 activation
    const unsigned short* Wt = (z == 0) ? Wtq : (z == 1) ? Wtk : Wtv;
    const float* bias        = (z == 0) ? bq  : (z == 1) ? bk  : bv;
    const int m0 = (z < 2) ? blockIdx.y * 128 : blockIdx.x * 128;
    const int n0 = (z < 2) ? blockIdx.x * 128 : blockIdx.y * 128;

    const int tid = threadIdx.x;
    const int w = tid >> 6, lane = tid & 63;
    const int l15 = lane & 15, quad = lane >> 4;
    const int wm = (w >> 1) * 64, wn = (w & 1) * 64;

    __shared__ unsigned short As[128 * 72];
    __shared__ unsigned short Bs[128 * 72];

    f32x4 acc[4][4];
    #pragma unroll
    for (int i = 0; i < 4; i++)
        #pragma unroll
        for (int j = 0; j < 4; j++) acc[i][j] = (f32x4){0.f, 0.f, 0.f, 0.f};

    for (int k0 = 0; k0 < 512; k0 += 64) {
        __syncthreads();
        // weight tile (bf16 copy): As for z<2, Bs for z==2
        {
            unsigned short* Wdst = (z < 2) ? As : Bs;
            const int wrow0 = (z < 2) ? m0 : n0;
            #pragma unroll
            for (int it = 0; it < 2; it++) {
                int lin = tid + it * 256;
                int row = lin >> 2, c2 = (lin & 3) * 2;
                *(uint4*)&Wdst[row * 72 + c2 * 8]     = *(const uint4*)&Wt[(wrow0 + row) * 512 + k0 + c2 * 8];
                *(uint4*)&Wdst[row * 72 + c2 * 8 + 8] = *(const uint4*)&Wt[(wrow0 + row) * 512 + k0 + c2 * 8 + 8];
            }
        }
        // activation tile (fp32 -> bf16 in flight): Bs for z<2, As for z==2
        {
            unsigned short* Xdst = (z < 2) ? Bs : As;
            const int xrow0 = (z < 2) ? n0 : m0;
            #pragma unroll
            for (int it = 0; it < 8; it++) {
                int lin = tid + it * 256;
                int row = lin >> 4, c4 = (lin & 15) * 4;
                float4 v = *(const float4*)&Xf[(xrow0 + row) * 512 + k0 + c4];
                uint2 pp; pp.x = pack_rn(v.x, v.y); pp.y = pack_rn(v.z, v.w);
                *(uint2*)&Xdst[row * 72 + c4] = pp;
            }
        }
        __syncthreads();
        #pragma unroll
        for (int kc = 0; kc < 2; kc++) {
            bf16x8 a[4], bb[4];
            #pragma unroll
            for (int i = 0; i < 4; i++)
                a[i] = *(const bf16x8*)&As[(wm + 16 * i + l15) * 72 + kc * 32 + quad * 8];
            #pragma unroll
            for (int j = 0; j < 4; j++)
                bb[j] = *(const bf16x8*)&Bs[(wn + 16 * j + l15) * 72 + kc * 32 + quad * 8];
            #pragma unroll
            for (int i = 0; i < 4; i++)
                #pragma unroll
                for (int j = 0; j < 4; j++)
                    acc[i][j] = __builtin_amdgcn_mfma_f32_16x16x32_bf16(a[i], bb[j], acc[i][j], 0, 0, 0);
        }
    }

    if (z == 2) {
        #pragma unroll
        for (int j = 0; j < 4; j++) {
            int N = n0 + wn + 16 * j + l15;
            float bv_ = bias[N];
            int h = N >> 6, d = N & 63;
            #pragma unroll
            for (int i = 0; i < 4; i++) {
                int Mb = m0 + wm + 16 * i + quad * 4;
                int b = Mb >> 11, s = Mb & 2047;
                uint2 o;
                o.x = pack_rn(acc[i][j][0] + bv_, acc[i][j][1] + bv_);
                o.y = pack_rn(acc[i][j][2] + bv_, acc[i][j][3] + bv_);
                *(uint2*)&VtG[((b * H_ + h) * 64 + d) * 2048 + s] = o;
            }
        }
    } else {
        unsigned short* dst = (z == 0) ? Qb : Kb;
        const float scale = (z == 0) ? QSCALE : 1.0f;
        #pragma unroll
        for (int j = 0; j < 4; j++) {
            int sg = n0 + wn + 16 * j + l15;
            int b = sg >> 11, s = sg & 2047;
            #pragma unroll
            for (int i = 0; i < 4; i++) {
                int F = m0 + wm + 16 * i + quad * 4;
                int h = F >> 6, d = F & 63;
                float4 b4 = *(const float4*)&bias[F];
                uint2 o;
                o.x = pack_rn((acc[i][j][0] + b4.x) * scale, (acc[i][j][1] + b4.y) * scale);
                o.y = pack_rn((acc[i][j][2] + b4.z) * scale, (acc[i][j][3] + b4.w) * scale);
                *(uint2*)&dst[((b * H_ + h) * 2048 + s) * 64 + d] = o;
            }
        }
    }
}

// ---------------------------------------------------------------------------
// Split-K MFMA flash attention, fixed-shift softmax (R8-proven structure:
// 2-D grid, K via double-buffered LDS with 1 barrier/tile, V direct from
// global, key-mask via per-wave LDS broadcast with register prefetch).
// Fixed shift (mq) makes chunk partials purely ADDITIVE; li via ones-MFMA.
// ---------------------------------------------------------------------------
__global__ __launch_bounds__(256, 4) void flash_mfma(
    const unsigned short* __restrict__ Qg, const unsigned short* __restrict__ Kg,
    const unsigned short* __restrict__ VtG, const float* __restrict__ maskF,
    unsigned short* __restrict__ O0, unsigned short* __restrict__ O1,
    float* __restrict__ Lpart)
{
    const int bh = blockIdx.y, b = bh >> 3, h = bh & 7;
    const int q0 = blockIdx.x * 128;
    const int z  = blockIdx.z;               // key chunk: [z*1024, z*1024+1024)
    const int kbeg = z * 1024;
    const int tid = threadIdx.x;
    const int w = tid >> 6, lane = tid & 63;
    const int l15 = lane & 15, quad = lane >> 4;

    __shared__ unsigned short Ks[2][64 * 72];    // double-buffered K tile [key][d]
    __shared__ unsigned short Ps[4][32 * 72];    // per-wave P region [q][key]
    __shared__ float Km[4][64];                  // per-wave key-mask broadcast

    const float* mfb = maskF + b * 2048;
    unsigned short* pw = &Ps[w][0];

    // Q fragments (B-operand) + query mask, resident
    bf16x8 qf[2][2];
    float mq[2];
    #pragma unroll
    for (int qb = 0; qb < 2; qb++) {
        int qrow = q0 + w * 32 + qb * 16 + l15;
        const unsigned short* p = &Qg[(bh * 2048 + qrow) * 64 + quad * 8];
        qf[qb][0] = *(const bf16x8*)p;
        qf[qb][1] = *(const bf16x8*)(p + 32);
        mq[qb] = mfb[qrow];
    }

    // ones fragment for the li-MFMA
    bf16x8 ones;
    #pragma unroll
    for (int i = 0; i < 8; i++) ones[i] = (__bf16)1.0f;

    // K staging: thread -> (row = tid>>2, 2 chunks at (tid&3)*2) of 64x64 tile
    const int srow = tid >> 2;
    const int sch  = (tid & 3) * 2;
    const unsigned short* kgb = Kg + (long)bh * 2048 * 64;

    *(uint4*)&Ks[0][srow * 72 + sch * 8]     = *(const uint4*)&kgb[(kbeg + srow) * 64 + sch * 8];
    *(uint4*)&Ks[0][srow * 72 + sch * 8 + 8] = *(const uint4*)&kgb[(kbeg + srow) * 64 + sch * 8 + 8];
    float mfreg = mfb[kbeg + lane];              // mask prefetch for tile 0

    f32x4 accO[2][4];
    f32x4 accL[2];
    #pragma unroll
    for (int qb = 0; qb < 2; qb++) {
        accL[qb] = (f32x4){0.f, 0.f, 0.f, 0.f};
        #pragma unroll
        for (int dt = 0; dt < 4; dt++) accO[qb][dt] = (f32x4){0.f, 0.f, 0.f, 0.f};
    }

    __syncthreads();

    for (int tl = 0; tl < 16; tl++) {
        const int kt = kbeg + tl * 64;
        const int ktn = (tl < 15) ? kt + 64 : kt;
        const int cur = tl & 1, nxt = cur ^ 1;

        // [A] global loads: V frags for THIS tile, K staging + mask for NEXT
        bf16x8 vf[4][2];
        #pragma unroll
        for (int dt = 0; dt < 4; dt++)
            #pragma unroll
            for (int kc = 0; kc < 2; kc++)
                vf[dt][kc] = *(const bf16x8*)&VtG[(bh * 64 + dt * 16 + l15) * 2048 + kt + kc * 32 + quad * 8];
        uint4 kst0 = *(const uint4*)&kgb[(ktn + srow) * 64 + sch * 8];
        uint4 kst1 = *(const uint4*)&kgb[(ktn + srow) * 64 + sch * 8 + 8];
        Km[w][lane] = mfreg;                 // this tile's mask -> per-wave LDS
        mfreg = mfb[ktn + lane];             // prefetch next tile's mask

        f32x4 kmf[4];
        #pragma unroll
        for (int nt = 0; nt < 4; nt++)
            kmf[nt] = *(const f32x4*)&Km[w][nt * 16 + quad * 4];

        // [B] QK from LDS buf[cur]: S^T (rows=key, cols=q)
        bf16x8 kf[4][2];
        #pragma unroll
        for (int nt = 0; nt < 4; nt++)
            #pragma unroll
            for (int kc = 0; kc < 2; kc++)
                kf[nt][kc] = *(const bf16x8*)&Ks[cur][(nt * 16 + l15) * 72 + kc * 32 + quad * 8];
        f32x4 sc[2][4];
        #pragma unroll
        for (int qb = 0; qb < 2; qb++)
            #pragma unroll
            for (int nt = 0; nt < 4; nt++) {
                sc[qb][nt] = kmf[nt] + mq[qb];   // masks as C-init: exact quantization
                #pragma unroll
                for (int kc = 0; kc < 2; kc++)
                    sc[qb][nt] = __builtin_amdgcn_mfma_f32_16x16x32_bf16(
                        kf[nt][kc], qf[qb][kc], sc[qb][nt], 0, 0, 0);
            }

        // [C] fixed-shift softmax: p = exp2(sc - mq). No max, no alpha.
        #pragma unroll
        for (int qb = 0; qb < 2; qb++) {
            #pragma unroll
            for (int nt = 0; nt < 4; nt++) {
                float p0 = __builtin_amdgcn_exp2f(sc[qb][nt][0] - mq[qb]);
                float p1 = __builtin_amdgcn_exp2f(sc[qb][nt][1] - mq[qb]);
                float p2 = __builtin_amdgcn_exp2f(sc[qb][nt][2] - mq[qb]);
                float p3 = __builtin_amdgcn_exp2f(sc[qb][nt][3] - mq[qb]);
                uint2 pp2;
                pp2.x = pack_rn(p0, p1);
                pp2.y = pack_rn(p2, p3);
                *(uint2*)&pw[(qb * 16 + l15) * 72 + nt * 16 + quad * 4] = pp2;
            }
        }

        // [D] PV + li: O^T += Vt x P^T ; li += ones x P^T
        #pragma unroll
        for (int qb = 0; qb < 2; qb++) {
            bf16x8 pf0 = *(const bf16x8*)&pw[(qb * 16 + l15) * 72 + quad * 8];
            bf16x8 pf1 = *(const bf16x8*)&pw[(qb * 16 + l15) * 72 + 32 + quad * 8];
            accL[qb] = __builtin_amdgcn_mfma_f32_16x16x32_bf16(ones, pf0, accL[qb], 0, 0, 0);
            accL[qb] = __builtin_amdgcn_mfma_f32_16x16x32_bf16(ones, pf1, accL[qb], 0, 0, 0);
            #pragma unroll
            for (int dt = 0; dt < 4; dt++) {
                accO[qb][dt] = __builtin_amdgcn_mfma_f32_16x16x32_bf16(
                    vf[dt][0], pf0, accO[qb][dt], 0, 0, 0);
                accO[qb][dt] = __builtin_amdgcn_mfma_f32_16x16x32_bf16(
                    vf[dt][1], pf1, accO[qb][dt], 0, 0, 0);
            }
        }

        // [E] commit next K tile to LDS, [F] barrier
        *(uint4*)&Ks[nxt][srow * 72 + sch * 8]     = kst0;
        *(uint4*)&Ks[nxt][srow * 72 + sch * 8 + 8] = kst1;
        __syncthreads();
    }

    // epilogue: UNNORMALIZED partial O (bf16) + partial li per q row
    unsigned short* Opz = z ? O1 : O0;
    float* Lz = Lpart + z * (32 * 2048);
    #pragma unroll
    for (int qb = 0; qb < 2; qb++) {
        int q = q0 + w * 32 + qb * 16 + l15;
        int obase = (b * 2048 + q) * 512 + h * 64 + quad * 4;
        #pragma unroll
        for (int dt = 0; dt < 4; dt++) {
            uint2 o;
            o.x = pack_rn(accO[qb][dt][0], accO[qb][dt][1]);
            o.y = pack_rn(accO[qb][dt][2], accO[qb][dt][3]);
            *(uint2*)&Opz[obase + dt * 16] = o;
        }
        if (quad == 0) Lz[bh * 2048 + q] = accL[qb][0];
    }
}

// ---------------------------------------------------------------------------
// Output projection with FUSED split-K combine: during B staging,
// B[s][k] = bf16((O0+O1) / (li0+li1)). h = k0>>6 is constant per k-iter so
// one inv per thread per iteration. A=Wto -> epilogue is float4 stores.
// ---------------------------------------------------------------------------
__global__ __launch_bounds__(256) void proj_out_mfma(
    const unsigned short* __restrict__ O0, const unsigned short* __restrict__ O1,
    const float* __restrict__ Lpart, const unsigned short* __restrict__ Wto,
    const float* __restrict__ bo, float* __restrict__ out)
{
    const int m0 = blockIdx.y * 128, n0 = blockIdx.x * 128;
    const int tid = threadIdx.x;
    const int w = tid >> 6, lane = tid & 63;
    const int l15 = lane & 15, quad = lane >> 4;
    const int wm = (w >> 1) * 64, wn = (w & 1) * 64;

    __shared__ unsigned short As[128 * 72];
    __shared__ unsigned short Bs[128 * 72];

    f32x4 acc[4][4];
    #pragma unroll
    for (int i = 0; i < 4; i++)
        #pragma unroll
        for (int j = 0; j < 4; j++) acc[i][j] = (f32x4){0.f, 0.f, 0.f, 0.f};

    for (int k0 = 0; k0 < 512; k0 += 64) {
        const int h = k0 >> 6;
        __syncthreads();
        #pragma unroll
        for (int it = 0; it < 2; it++) {
            int lin = tid + it * 256;
            int row = lin >> 2, c2 = (lin & 3) * 2;
            // A: Wto bf16 copy
            *(uint4*)&As[row * 72 + c2 * 8]     = *(const uint4*)&Wto[(m0 + row) * 512 + k0 + c2 * 8];
            *(uint4*)&As[row * 72 + c2 * 8 + 8] = *(const uint4*)&Wto[(m0 + row) * 512 + k0 + c2 * 8 + 8];
            // B: fused combine of split-K partials
            int srow = n0 + row;
            int b = srow >> 11, s = srow & 2047;
            int li_idx = ((b * 8 + h) << 11) + s;
            float inv = 1.f / (Lpart[li_idx] + Lpart[32 * 2048 + li_idx]);
            long gofs = (long)srow * 512 + k0 + c2 * 8;
            #pragma unroll
            for (int half = 0; half < 2; half++) {
                uint4 a4 = *(const uint4*)&O0[gofs + half * 8];
                uint4 c4 = *(const uint4*)&O1[gofs + half * 8];
                uint4 o4;
                o4.x = pack_rn((b2f_lo(a4.x) + b2f_lo(c4.x)) * inv,
                               (b2f_hi(a4.x) + b2f_hi(c4.x)) * inv);
                o4.y = pack_rn((b2f_lo(a4.y) + b2f_lo(c4.y)) * inv,
                               (b2f_hi(a4.y) + b2f_hi(c4.y)) * inv);
                o4.z = pack_rn((b2f_lo(a4.z) + b2f_lo(c4.z)) * inv,
                               (b2f_hi(a4.z) + b2f_hi(c4.z)) * inv);
                o4.w = pack_rn((b2f_lo(a4.w) + b2f_lo(c4.w)) * inv,
                               (b2f_hi(a4.w) + b2f_hi(c4.w)) * inv);
                *(uint4*)&Bs[row * 72 + c2 * 8 + half * 8] = o4;
            }
        }
        __syncthreads();
        #pragma unroll
        for (int kc = 0; kc < 2; kc++) {
            bf16x8 a[4], bb[4];
            #pragma unroll
            for (int i = 0; i < 4; i++)
                a[i] = *(const bf16x8*)&As[(wm + 16 * i + l15) * 72 + kc * 32 + quad * 8];
            #pragma unroll
            for (int j = 0; j < 4; j++)
                bb[j] = *(const bf16x8*)&Bs[(wn + 16 * j + l15) * 72 + kc * 32 + quad * 8];
            #pragma unroll
            for (int i = 0; i < 4; i++)
                #pragma unroll
                for (int j = 0; j < 4; j++)
                    acc[i][j] = __builtin_amdgcn_mfma_f32_16x16x32_bf16(a[i], bb[j], acc[i][j], 0, 0, 0);
        }
    }

    #pragma unroll
    for (int j = 0; j < 4; j++) {
        int sg = n0 + wn + 16 * j + l15;
        #pragma unroll
        for (int i = 0; i < 4; i++) {
            int F = m0 + wm + 16 * i + quad * 4;
            float4 b4 = *(const float4*)&bo[F];
            float4 vv;
            vv.x = acc[i][j][0] + b4.x;
            vv.y = acc[i][j][1] + b4.y;
            vv.z = acc[i][j][2] + b4.z;
            vv.w = acc[i][j][3] + b4.w;
            *(float4*)&out[sg * 512 + F] = vv;
        }
    }
}

extern "C" void kernel_launch(void* const* d_in, const int* in_sizes, int n_in,
                              void* d_out, int out_size, void* d_ws, size_t ws_size,
                              hipStream_t stream)
{
    const float* query = (const float*)d_in[0];
    const float* value = (const float*)d_in[1];
    const int*   amask = (const int*)d_in[2];
    const float* Wq = (const float*)d_in[3];
    const float* bq = (const float*)d_in[4];
    const float* Wk = (const float*)d_in[5];
    const float* bk = (const float*)d_in[6];
    const float* Wv = (const float*)d_in[7];
    const float* bv = (const float*)d_in[8];
    const float* Wo = (const float*)d_in[9];
    const float* bo = (const float*)d_in[10];
    float* out = (float*)d_out;

    char* ws = (char*)d_ws;
    const size_t MB = 1 << 20;
    unsigned short* O0  = (unsigned short*)(ws);                  // 8 MB split-K partial O
    unsigned short* O1  = (unsigned short*)(ws + 8 * MB);         // 8 MB
    unsigned short* Wtq = (unsigned short*)(ws + 16 * MB);        // 0.5 MB each
    unsigned short* Wtk = (unsigned short*)(ws + 16 * MB + MB / 2);
    unsigned short* Wtv = (unsigned short*)(ws + 17 * MB);
    unsigned short* Wto = (unsigned short*)(ws + 17 * MB + MB / 2);
    unsigned short* Qb  = (unsigned short*)(ws + 18 * MB);        // 8 MB (bh,s,d)
    unsigned short* Kb  = (unsigned short*)(ws + 26 * MB);        // 8 MB (bh,s,d)
    unsigned short* VtG = (unsigned short*)(ws + 34 * MB);        // 8 MB (bh,d,s)
    float*          mF  = (float*)(ws + 50 * MB);                 // 32 KB float mask
    float*          Lp  = (float*)(ws + 51 * MB);                 // 512 KB li partials

    cast_wt<<<dim3(8, 8, 5), 256, 0, stream>>>(Wq, Wk, Wv, Wo, amask,
                                               Wtq, Wtk, Wtv, Wto, mF);
    proj_qkv_mfma<<<dim3(64, 4, 3), 256, 0, stream>>>(query, value, Wtq, Wtk, Wtv,
                                                      bq, bk, bv, Qb, Kb, VtG);
    flash_mfma<<<dim3(16, 32, 2), 256, 0, stream>>>(Qb, Kb, VtG, mF, O0, O1, Lp);
    proj_out_mfma<<<dim3(64, 4), 256, 0, stream>>>(O0, O1, Lp, Wto, bo, out);
}